// Round 1
// baseline (1627.708 us; speedup 1.0000x reference)
//
#include <hip/hip_runtime.h>

// HyperNetSIR: x(N,3) f32, H(E,N) f32 0/1 mask (density 0.002), beta(N), gamma(N), steps(int)
// out: (steps, N, 3) f32 trajectory.
//
// Strategy:
//  1. Extract sparse adjacency from H once per launch (H is restored from
//     pristine each timed call, so the 400MB scan is unavoidable; wide grid
//     to saturate HBM).
//  2. Run all steps-1 sparse SpMV+pointwise steps inside ONE persistent
//     kernel (64 blocks x 1024 threads, guaranteed co-resident on 256 CUs)
//     with a hand-rolled device-scope grid barrier. This removes ~98 small
//     kernel launches whose dispatch/serialization overhead dominated the
//     previous version (each step's real work is ~1MB of L2-resident
//     gathers, i.e. ~1-2us).

#define EDGE_CAP 96   // max nodes per edge (mean 40, sigma 6.3 -> ~9 sigma headroom)
#define NODE_CAP 32   // max edges per node (mean 10, sigma 3.2 -> ~7 sigma headroom)
#define COOP_BLOCKS 64
#define COOP_THREADS 1024

__global__ void zero_counts_kernel(int* edge_cnt, int* node_cnt, unsigned* bar,
                                   int n_edges, int n_nodes) {
    int i = blockIdx.x * blockDim.x + threadIdx.x;
    if (i == 0) *bar = 0u;            // grid-barrier counter (ws is poisoned each call)
    if (i < n_edges) edge_cnt[i] = 0;
    if (i < n_nodes) node_cnt[i] = 0;
}

// One block per edge row. Scan the row of H with float4 loads, append nonzero
// column indices to edge_nodes[e], and append e to node_edges[col] (atomics).
__global__ void build_adjacency_kernel(const float* __restrict__ H,
                                       int* __restrict__ edge_cnt,
                                       int* __restrict__ edge_nodes,
                                       int* __restrict__ node_cnt,
                                       int* __restrict__ node_edges,
                                       int n_nodes) {
    const int e = blockIdx.x;
    const float* row = H + (size_t)e * n_nodes;
    const int n4 = n_nodes >> 2;
    const float4* row4 = (const float4*)row;
    for (int c4 = threadIdx.x; c4 < n4; c4 += blockDim.x) {
        float4 v = row4[c4];
        int cbase = c4 << 2;
        if (v.x != 0.0f) {
            int p = atomicAdd(&edge_cnt[e], 1);
            if (p < EDGE_CAP) edge_nodes[e * EDGE_CAP + p] = cbase;
            int q = atomicAdd(&node_cnt[cbase], 1);
            if (q < NODE_CAP) node_edges[cbase * NODE_CAP + q] = e;
        }
        if (v.y != 0.0f) {
            int c = cbase + 1;
            int p = atomicAdd(&edge_cnt[e], 1);
            if (p < EDGE_CAP) edge_nodes[e * EDGE_CAP + p] = c;
            int q = atomicAdd(&node_cnt[c], 1);
            if (q < NODE_CAP) node_edges[c * NODE_CAP + q] = e;
        }
        if (v.z != 0.0f) {
            int c = cbase + 2;
            int p = atomicAdd(&edge_cnt[e], 1);
            if (p < EDGE_CAP) edge_nodes[e * EDGE_CAP + p] = c;
            int q = atomicAdd(&node_cnt[c], 1);
            if (q < NODE_CAP) node_edges[c * NODE_CAP + q] = e;
        }
        if (v.w != 0.0f) {
            int c = cbase + 3;
            int p = atomicAdd(&edge_cnt[e], 1);
            if (p < EDGE_CAP) edge_nodes[e * EDGE_CAP + p] = c;
            int q = atomicAdd(&node_cnt[c], 1);
            if (q < NODE_CAP) node_edges[c * NODE_CAP + q] = e;
        }
    }
    // tail (n_nodes not multiple of 4)
    if (threadIdx.x == 0) {
        for (int c = n4 << 2; c < n_nodes; ++c) {
            if (row[c] != 0.0f) {
                int p = atomicAdd(&edge_cnt[e], 1);
                if (p < EDGE_CAP) edge_nodes[e * EDGE_CAP + p] = c;
                int q = atomicAdd(&node_cnt[c], 1);
                if (q < NODE_CAP) node_edges[c * NODE_CAP + q] = e;
            }
        }
    }
}

// Device-scope grid barrier. All COOP_BLOCKS blocks are co-resident
// (64 blocks << 256 CUs, no LDS, low VGPR), so spinning is safe.
// agent-scope fences handle cross-XCD L2 non-coherence (release: L2
// writeback; acquire: L2/L1 invalidate) -- same mechanism ROCm's
// cooperative-groups grid.sync() uses.
__device__ __forceinline__ void grid_sync(unsigned* bar, unsigned& target) {
    __syncthreads();                  // all block's memory ops drained (vmcnt 0)
    target += (unsigned)gridDim.x;
    if (threadIdx.x == 0) {
        __builtin_amdgcn_fence(__ATOMIC_RELEASE, "agent");
        atomicAdd(bar, 1u);
        while (__hip_atomic_load(bar, __ATOMIC_RELAXED, __HIP_MEMORY_SCOPE_AGENT) < target)
            __builtin_amdgcn_s_sleep(2);
        __builtin_amdgcn_fence(__ATOMIC_ACQUIRE, "agent");
    }
    __syncthreads();
}

// All SIR steps in one persistent kernel.
// Edge phase: y[e] = sum_{n in e} I[n]  (16-lane group per edge).
// Node phase: z[n] = sum_{e ni n} y[e]; SIR update + clamp + renorm; traj write.
__global__ __launch_bounds__(COOP_THREADS) void sir_steps_kernel(
        const float* __restrict__ x,
        const int* __restrict__ edge_cnt, const int* __restrict__ edge_nodes,
        const int* __restrict__ node_cnt, const int* __restrict__ node_edges,
        const float* __restrict__ beta, const float* __restrict__ gamma,
        float* __restrict__ y, float* __restrict__ S, float* __restrict__ I,
        float* __restrict__ R, float* __restrict__ out,
        int n_nodes, int n_edges, int steps, unsigned* bar) {
    const int tid = blockIdx.x * blockDim.x + threadIdx.x;
    const int nthreads = gridDim.x * blockDim.x;
    unsigned bar_target = 0;

    // init: unpack state columns + traj[0] = x
    for (int n = tid; n < n_nodes; n += nthreads) {
        float s = x[n * 3 + 0], iv = x[n * 3 + 1], r = x[n * 3 + 2];
        S[n] = s; I[n] = iv; R[n] = r;
        out[n * 3 + 0] = s; out[n * 3 + 1] = iv; out[n * 3 + 2] = r;
    }
    grid_sync(bar, bar_target);

    const int g  = tid >> 4;              // 16-lane group id
    const int gl = threadIdx.x & 15;      // lane within group
    const int ngroups = nthreads >> 4;

    for (int t = 1; t < steps; ++t) {
        // ---- edge phase ----
        for (int e = g; e < n_edges; e += ngroups) {
            int cnt = min(edge_cnt[e], EDGE_CAP);
            const int* en = edge_nodes + e * EDGE_CAP;
            float s = 0.0f;
            for (int i = gl; i < cnt; i += 16) s += I[en[i]];
            s += __shfl_down(s, 8, 16);
            s += __shfl_down(s, 4, 16);
            s += __shfl_down(s, 2, 16);
            s += __shfl_down(s, 1, 16);
            if (gl == 0) y[e] = s;
        }
        grid_sync(bar, bar_target);

        // ---- node phase ----
        float* out_t = out + (size_t)t * n_nodes * 3;
        for (int n = tid; n < n_nodes; n += nthreads) {
            int cnt = min(node_cnt[n], NODE_CAP);
            const int* ne = node_edges + n * NODE_CAP;
            float z = 0.0f;
            for (int i = 0; i < cnt; ++i) z += y[ne[i]];
            float s = S[n], iv = I[n], r = R[n];
            float nc = beta[n] * s * z;
            float nr = gamma[n] * iv;
            float s2 = fmaxf(s - nc, 0.0f);
            float i2 = fmaxf(iv + nc - nr, 0.0f);
            float r2 = fmaxf(r + nr, 0.0f);
            float inv = 1.0f / (s2 + i2 + r2);
            s2 *= inv; i2 *= inv; r2 *= inv;
            S[n] = s2; I[n] = i2; R[n] = r2;
            out_t[n * 3 + 0] = s2; out_t[n * 3 + 1] = i2; out_t[n * 3 + 2] = r2;
        }
        if (t + 1 < steps) grid_sync(bar, bar_target);  // next edge phase reads I
    }
}

extern "C" void kernel_launch(void* const* d_in, const int* in_sizes, int n_in,
                              void* d_out, int out_size, void* d_ws, size_t ws_size,
                              hipStream_t stream) {
    const float* x     = (const float*)d_in[0];
    const float* H     = (const float*)d_in[1];
    const float* beta  = (const float*)d_in[2];
    const float* gamma = (const float*)d_in[3];
    float* out = (float*)d_out;

    const int n_nodes = in_sizes[0] / 3;                 // 20000
    const int n_edges = in_sizes[1] / n_nodes;           // 5000
    const int steps   = out_size / in_sizes[0];          // 50

    // workspace carve-up (ints/floats are both 4B)
    char* ws = (char*)d_ws;
    unsigned* bar     = (unsigned*)ws;                    ws += 64;  // keep alignment
    int*   edge_cnt   = (int*)ws;                         ws += (size_t)n_edges * 4;
    int*   node_cnt   = (int*)ws;                         ws += (size_t)n_nodes * 4;
    int*   edge_nodes = (int*)ws;                         ws += (size_t)n_edges * EDGE_CAP * 4;
    int*   node_edges = (int*)ws;                         ws += (size_t)n_nodes * NODE_CAP * 4;
    float* y          = (float*)ws;                       ws += (size_t)n_edges * 4;
    float* S          = (float*)ws;                       ws += (size_t)n_nodes * 4;
    float* I          = (float*)ws;                       ws += (size_t)n_nodes * 4;
    float* R          = (float*)ws;                       ws += (size_t)n_nodes * 4;

    // 1. zero adjacency counters + barrier (ws is poisoned 0xAA each call)
    {
        int mx = max(n_edges, n_nodes);
        zero_counts_kernel<<<(mx + 255) / 256, 256, 0, stream>>>(edge_cnt, node_cnt, bar,
                                                                 n_edges, n_nodes);
    }
    // 2. extract sparsity of H (the one unavoidable 400MB scan; wide grid for BW)
    build_adjacency_kernel<<<n_edges, 256, 0, stream>>>(H, edge_cnt, edge_nodes,
                                                        node_cnt, node_edges, n_nodes);
    // 3. all SIR steps in one persistent kernel with internal grid barriers
    sir_steps_kernel<<<COOP_BLOCKS, COOP_THREADS, 0, stream>>>(
        x, edge_cnt, edge_nodes, node_cnt, node_edges, beta, gamma,
        y, S, I, R, out, n_nodes, n_edges, steps, bar);
}

// Round 2
// 1490.270 us; speedup vs baseline: 1.0922x; 1.0922x over previous
//
#include <hip/hip_runtime.h>

// HyperNetSIR: x(N,3) f32, H(E,N) f32 0/1 mask (density 0.002), beta(N), gamma(N), steps(int)
// out: (steps, N, 3) f32 trajectory.
//
// Strategy:
//  1. Extract sparse adjacency from H once per launch (H is restored from
//     pristine each timed call, so the 400MB scan is unavoidable; wide grid
//     to saturate HBM).
//  2. Run all steps-1 sparse steps inside ONE persistent kernel with a
//     FENCE-FREE grid barrier. Round-1 lesson: agent-scope fences emit
//     buffer_wbl2 + buffer_inv on every barrier (~11us each: synchronous L2
//     writeback + full L1/L2 invalidate -> adjacency re-fetched from L3 every
//     phase). Instead, only the truly shared arrays (I: 80KB, y: 20KB) go
//     through the coherence point via sc-flagged relaxed agent atomics; the
//     barrier is s_waitcnt vmcnt(0) + one agent atomicAdd + poll. Read-only
//     adjacency stays hot in L1/L2 for all 49 steps. S,R live in registers
//     (each thread owns one node and is the only reader/writer).

#define EDGE_CAP 96   // max nodes per edge (mean 40, sigma 6.3 -> ~9 sigma headroom)
#define NODE_CAP 32   // max edges per node (mean 10, sigma 3.2 -> ~7 sigma headroom)
#define COOP_BLOCKS 256
#define COOP_THREADS 512

__global__ void zero_counts_kernel(int* edge_cnt, int* node_cnt, unsigned* bar,
                                   int n_edges, int n_nodes) {
    int i = blockIdx.x * blockDim.x + threadIdx.x;
    if (i == 0) *bar = 0u;            // grid-barrier counter (ws is poisoned each call)
    if (i < n_edges) edge_cnt[i] = 0;
    if (i < n_nodes) node_cnt[i] = 0;
}

// One block per edge row. Scan the row of H with float4 loads, append nonzero
// column indices to edge_nodes[e], and append e to node_edges[col] (atomics).
__global__ void build_adjacency_kernel(const float* __restrict__ H,
                                       int* __restrict__ edge_cnt,
                                       int* __restrict__ edge_nodes,
                                       int* __restrict__ node_cnt,
                                       int* __restrict__ node_edges,
                                       int n_nodes) {
    const int e = blockIdx.x;
    const float* row = H + (size_t)e * n_nodes;
    const int n4 = n_nodes >> 2;
    const float4* row4 = (const float4*)row;
    for (int c4 = threadIdx.x; c4 < n4; c4 += blockDim.x) {
        float4 v = row4[c4];
        int cbase = c4 << 2;
        if (v.x != 0.0f) {
            int p = atomicAdd(&edge_cnt[e], 1);
            if (p < EDGE_CAP) edge_nodes[e * EDGE_CAP + p] = cbase;
            int q = atomicAdd(&node_cnt[cbase], 1);
            if (q < NODE_CAP) node_edges[cbase * NODE_CAP + q] = e;
        }
        if (v.y != 0.0f) {
            int c = cbase + 1;
            int p = atomicAdd(&edge_cnt[e], 1);
            if (p < EDGE_CAP) edge_nodes[e * EDGE_CAP + p] = c;
            int q = atomicAdd(&node_cnt[c], 1);
            if (q < NODE_CAP) node_edges[c * NODE_CAP + q] = e;
        }
        if (v.z != 0.0f) {
            int c = cbase + 2;
            int p = atomicAdd(&edge_cnt[e], 1);
            if (p < EDGE_CAP) edge_nodes[e * EDGE_CAP + p] = c;
            int q = atomicAdd(&node_cnt[c], 1);
            if (q < NODE_CAP) node_edges[c * NODE_CAP + q] = e;
        }
        if (v.w != 0.0f) {
            int c = cbase + 3;
            int p = atomicAdd(&edge_cnt[e], 1);
            if (p < EDGE_CAP) edge_nodes[e * EDGE_CAP + p] = c;
            int q = atomicAdd(&node_cnt[c], 1);
            if (q < NODE_CAP) node_edges[c * NODE_CAP + q] = e;
        }
    }
    // tail (n_nodes not multiple of 4)
    if (threadIdx.x == 0) {
        for (int c = n4 << 2; c < n_nodes; ++c) {
            if (row[c] != 0.0f) {
                int p = atomicAdd(&edge_cnt[e], 1);
                if (p < EDGE_CAP) edge_nodes[e * EDGE_CAP + p] = c;
                int q = atomicAdd(&node_cnt[c], 1);
                if (q < NODE_CAP) node_edges[c * NODE_CAP + q] = e;
            }
        }
    }
}

// Coherent (cross-XCD) access helpers: sc-flagged, bypass non-coherent L1/L2.
__device__ __forceinline__ float coh_load(const float* p) {
    return __hip_atomic_load(p, __ATOMIC_RELAXED, __HIP_MEMORY_SCOPE_AGENT);
}
__device__ __forceinline__ void coh_store(float* p, float v) {
    __hip_atomic_store(p, v, __ATOMIC_RELAXED, __HIP_MEMORY_SCOPE_AGENT);
}

// Fence-free grid barrier. All COOP_BLOCKS blocks are co-resident (tiny
// resource footprint), so spinning is safe. Correctness: every cross-block
// value is exchanged via coherent (sc-flagged) loads/stores, so no cache
// writeback/invalidate is needed -- only (a) completion of this thread's
// coherent stores (s_waitcnt vmcnt(0)) before signaling arrival, and (b) the
// arrival counter itself being an agent-scope RMW.
__device__ __forceinline__ void grid_sync(unsigned* bar, unsigned& target) {
    asm volatile("s_waitcnt vmcnt(0)" ::: "memory");  // my coherent stores done
    __syncthreads();
    target += (unsigned)gridDim.x;
    if (threadIdx.x == 0) {
        __hip_atomic_fetch_add(bar, 1u, __ATOMIC_RELAXED, __HIP_MEMORY_SCOPE_AGENT);
        while (__hip_atomic_load(bar, __ATOMIC_RELAXED, __HIP_MEMORY_SCOPE_AGENT) < target)
            __builtin_amdgcn_s_sleep(1);
    }
    __syncthreads();
    asm volatile("" ::: "memory");
}

// All SIR steps in one persistent kernel.
// Edge phase: y[e] = sum_{n in e} I[n]  (16-lane group per edge).
// Node phase: z[n] = sum_{e ni n} y[e]; SIR update + clamp + renorm; traj write.
// Requires gridDim*blockDim >= n_nodes (each thread owns <=1 node; S,R in regs).
__global__ __launch_bounds__(COOP_THREADS) void sir_steps_kernel(
        const float* __restrict__ x,
        const int* __restrict__ edge_cnt, const int* __restrict__ edge_nodes,
        const int* __restrict__ node_cnt, const int* __restrict__ node_edges,
        const float* __restrict__ beta, const float* __restrict__ gamma,
        float* __restrict__ y, float* __restrict__ I,
        float* __restrict__ out,
        int n_nodes, int n_edges, int steps, unsigned* bar) {
    const int tid = blockIdx.x * blockDim.x + threadIdx.x;
    unsigned bar_target = 0;

    // --- init: this thread's node state into registers; publish I; traj[0] ---
    const int n = tid;
    const bool own = (n < n_nodes);
    float s = 0.0f, iv = 0.0f, r = 0.0f, bet = 0.0f, gam = 0.0f;
    int ncnt = 0;
    const int* ne = node_edges;
    if (own) {
        s  = x[n * 3 + 0];
        iv = x[n * 3 + 1];
        r  = x[n * 3 + 2];
        bet = beta[n];
        gam = gamma[n];
        coh_store(&I[n], iv);
        out[n * 3 + 0] = s; out[n * 3 + 1] = iv; out[n * 3 + 2] = r;
        ne = node_edges + n * NODE_CAP;
    }
    grid_sync(bar, bar_target);
    if (own) ncnt = min(node_cnt[n], NODE_CAP);   // cached read, after build visible

    // edge-group mapping: 16 lanes per edge
    const int g  = tid >> 4;
    const int gl = threadIdx.x & 15;
    const int ngroups = (gridDim.x * blockDim.x) >> 4;

    for (int t = 1; t < steps; ++t) {
        // ---- edge phase: y[e] = sum I over edge members ----
        for (int e = g; e < n_edges; e += ngroups) {
            int cnt = min(edge_cnt[e], EDGE_CAP);          // L1-hot after step 1
            const int* en = edge_nodes + e * EDGE_CAP;     // L1-hot after step 1
            float acc = 0.0f;
            for (int i = gl; i < cnt; i += 16) acc += coh_load(&I[en[i]]);
            acc += __shfl_down(acc, 8, 16);
            acc += __shfl_down(acc, 4, 16);
            acc += __shfl_down(acc, 2, 16);
            acc += __shfl_down(acc, 1, 16);
            if (gl == 0) coh_store(&y[e], acc);
        }
        grid_sync(bar, bar_target);

        // ---- node phase: gather y, SIR update in regs, publish I, write traj ----
        if (own) {
            float z = 0.0f;
            for (int i = 0; i < ncnt; ++i) z += coh_load(&y[ne[i]]);
            float nc = bet * s * z;
            float nr = gam * iv;
            float s2 = fmaxf(s - nc, 0.0f);
            float i2 = fmaxf(iv + nc - nr, 0.0f);
            float r2 = fmaxf(r + nr, 0.0f);
            float inv = 1.0f / (s2 + i2 + r2);
            s = s2 * inv; iv = i2 * inv; r = r2 * inv;
            coh_store(&I[n], iv);
            float* out_t = out + (size_t)t * n_nodes * 3;
            out_t[n * 3 + 0] = s; out_t[n * 3 + 1] = iv; out_t[n * 3 + 2] = r;
        }
        if (t + 1 < steps) grid_sync(bar, bar_target);  // next edge phase reads I
    }
}

extern "C" void kernel_launch(void* const* d_in, const int* in_sizes, int n_in,
                              void* d_out, int out_size, void* d_ws, size_t ws_size,
                              hipStream_t stream) {
    const float* x     = (const float*)d_in[0];
    const float* H     = (const float*)d_in[1];
    const float* beta  = (const float*)d_in[2];
    const float* gamma = (const float*)d_in[3];
    float* out = (float*)d_out;

    const int n_nodes = in_sizes[0] / 3;                 // 20000
    const int n_edges = in_sizes[1] / n_nodes;           // 5000
    const int steps   = out_size / in_sizes[0];          // 50

    // workspace carve-up (ints/floats are both 4B)
    char* ws = (char*)d_ws;
    unsigned* bar     = (unsigned*)ws;                    ws += 64;  // keep alignment
    int*   edge_cnt   = (int*)ws;                         ws += (size_t)n_edges * 4;
    int*   node_cnt   = (int*)ws;                         ws += (size_t)n_nodes * 4;
    int*   edge_nodes = (int*)ws;                         ws += (size_t)n_edges * EDGE_CAP * 4;
    int*   node_edges = (int*)ws;                         ws += (size_t)n_nodes * NODE_CAP * 4;
    float* y          = (float*)ws;                       ws += (size_t)n_edges * 4;
    float* I          = (float*)ws;                       ws += (size_t)n_nodes * 4;

    // 1. zero adjacency counters + barrier (ws is poisoned 0xAA each call)
    {
        int mx = max(n_edges, n_nodes);
        zero_counts_kernel<<<(mx + 255) / 256, 256, 0, stream>>>(edge_cnt, node_cnt, bar,
                                                                 n_edges, n_nodes);
    }
    // 2. extract sparsity of H (the one unavoidable 400MB scan; wide grid for BW)
    build_adjacency_kernel<<<n_edges, 256, 0, stream>>>(H, edge_cnt, edge_nodes,
                                                        node_cnt, node_edges, n_nodes);
    // 3. all SIR steps in one persistent kernel with fence-free grid barriers
    sir_steps_kernel<<<COOP_BLOCKS, COOP_THREADS, 0, stream>>>(
        x, edge_cnt, edge_nodes, node_cnt, node_edges, beta, gamma,
        y, I, out, n_nodes, n_edges, steps, bar);
}

// Round 3
// 1087.551 us; speedup vs baseline: 1.4967x; 1.3703x over previous
//
#include <hip/hip_runtime.h>

// HyperNetSIR: x(N,3) f32, H(E,N) f32 0/1 mask (density 0.002), beta(N), gamma(N), steps(int)
// out: (steps, N, 3) f32 trajectory.
//
// v3 strategy:
//  * build_adjacency: LDS-compacted per-row nonzero extraction (one branch per
//    float4, LDS atomics), then coalesced writeout + batched global atomics.
//    Removes the per-nonzero global-atomic wave stalls of v2.
//  * sir_steps: persistent kernel, 256 blocks x 512 threads (1 block/CU).
//    - chunked ownership: block b owns nodes [b*79..), edges [b*20..), work
//      spread across all 8 waves of every block (slot = wave + 8*lane).
//    - adjacency indices preloaded into REGISTERS once (unrolled, padded with
//      a dummy zero-element), so per-step gathers are branch-free independent
//      coherent loads -> full memory-level parallelism at L3 latency.
//    - cross-XCD data (I: 80KB, y: 20KB) via sc-flagged relaxed agent atomics
//      (bypass non-coherent L1/L2); everything else stays cache-hot.
//    - two-level barrier tree: 16 group counters (separate 64B lines) + root;
//      arrive/wait split so trajectory stores overlap the spin.

#define EDGE_CAP 96   // max nodes per edge (mean 40, sigma 6.3)
#define NODE_CAP 32   // max edges per node (mean 10, sigma 3.2)
#define NIDX_REG 16   // node-adjacency indices held in registers (P(cnt>16) ~ 3%)
#define COOP_BLOCKS 256
#define COOP_THREADS 512
#define BAR_UINTS 512      // 2KB barrier region
#define GRP_STRIDE 16      // uints -> one 64B line per group counter
#define NGRP 16            // 16 groups x 16 blocks

__global__ void zero_counts_kernel(int* edge_cnt, int* node_cnt, unsigned* bar,
                                   int n_edges, int n_nodes) {
    int i = blockIdx.x * blockDim.x + threadIdx.x;
    if (i < BAR_UINTS) bar[i] = 0u;
    if (i < n_edges) edge_cnt[i] = 0;
    if (i < n_nodes) node_cnt[i] = 0;
}

// One block per edge row. Compact nonzero columns into LDS (cheap LDS atomics),
// then write the edge list coalesced and do the node-side scatter with one
// batched wave of global atomics.
__global__ void build_adjacency_kernel(const float* __restrict__ H,
                                       int* __restrict__ edge_cnt,
                                       int* __restrict__ edge_nodes,
                                       int* __restrict__ node_cnt,
                                       int* __restrict__ node_edges,
                                       int n_nodes) {
    __shared__ int cnt;
    __shared__ int cols[EDGE_CAP];
    const int e = blockIdx.x;
    if (threadIdx.x == 0) cnt = 0;
    __syncthreads();
    const uint4* row4 = (const uint4*)(H + (size_t)e * n_nodes);
    const int n4 = n_nodes >> 2;
    for (int c4 = threadIdx.x; c4 < n4; c4 += blockDim.x) {
        uint4 v = row4[c4];
        if ((v.x | v.y | v.z | v.w) != 0u) {   // H is a 0/1 mask; bit test ok
            int cbase = c4 << 2;
            if (v.x) { int p = atomicAdd(&cnt, 1); if (p < EDGE_CAP) cols[p] = cbase; }
            if (v.y) { int p = atomicAdd(&cnt, 1); if (p < EDGE_CAP) cols[p] = cbase + 1; }
            if (v.z) { int p = atomicAdd(&cnt, 1); if (p < EDGE_CAP) cols[p] = cbase + 2; }
            if (v.w) { int p = atomicAdd(&cnt, 1); if (p < EDGE_CAP) cols[p] = cbase + 3; }
        }
    }
    if (threadIdx.x == 0) {   // tail (n_nodes not multiple of 4)
        const float* row = H + (size_t)e * n_nodes;
        for (int c = n4 << 2; c < n_nodes; ++c)
            if (row[c] != 0.0f) { int p = atomicAdd(&cnt, 1); if (p < EDGE_CAP) cols[p] = c; }
    }
    __syncthreads();
    int cn = min(cnt, EDGE_CAP);
    if (threadIdx.x == 0) edge_cnt[e] = cn;
    for (int i = threadIdx.x; i < cn; i += blockDim.x) {
        int c = cols[i];
        edge_nodes[e * EDGE_CAP + i] = c;
        int q = atomicAdd(&node_cnt[c], 1);           // device-scope, batched
        if (q < NODE_CAP) node_edges[c * NODE_CAP + q] = e;
    }
}

// Coherent (cross-XCD) access helpers: sc-flagged, bypass non-coherent L1/L2.
__device__ __forceinline__ float coh_load(const float* p) {
    return __hip_atomic_load(p, __ATOMIC_RELAXED, __HIP_MEMORY_SCOPE_AGENT);
}
__device__ __forceinline__ void coh_storef(float* p, float v) {
    __hip_atomic_store(p, v, __ATOMIC_RELAXED, __HIP_MEMORY_SCOPE_AGENT);
}

// Two-level tree barrier (16 groups x 16 blocks + root), arrive/wait split.
// All blocks co-resident (1 block/CU). All cross-block data goes through
// coherent (sc-flagged) accesses, so no cache flush/invalidate is needed:
// arrive = drain my coherent stores (vmcnt 0) + one agent atomicAdd to my
// group line; wait = group leader promotes to root, everyone polls root.
__device__ __forceinline__ void bar_arrive(unsigned* bar) {
    asm volatile("s_waitcnt vmcnt(0)" ::: "memory");
    __syncthreads();
    if (threadIdx.x == 0)
        __hip_atomic_fetch_add(&bar[(blockIdx.x >> 4) * GRP_STRIDE], 1u,
                               __ATOMIC_RELAXED, __HIP_MEMORY_SCOPE_AGENT);
}
__device__ __forceinline__ void bar_wait(unsigned* bar, unsigned phase) {
    if (threadIdx.x == 0) {
        unsigned* root = &bar[NGRP * GRP_STRIDE];
        if ((blockIdx.x & 15) == 0) {   // leader of group blockIdx.x>>4
            unsigned* grp = &bar[(blockIdx.x >> 4) * GRP_STRIDE];
            while (__hip_atomic_load(grp, __ATOMIC_RELAXED, __HIP_MEMORY_SCOPE_AGENT) < 16u * phase)
                __builtin_amdgcn_s_sleep(1);
            __hip_atomic_fetch_add(root, 1u, __ATOMIC_RELAXED, __HIP_MEMORY_SCOPE_AGENT);
        }
        while (__hip_atomic_load(root, __ATOMIC_RELAXED, __HIP_MEMORY_SCOPE_AGENT) < (unsigned)NGRP * phase)
            __builtin_amdgcn_s_sleep(1);
    }
    __syncthreads();
    asm volatile("" ::: "memory");
}

// All SIR steps in one persistent kernel.
// Requires: n_nodes <= 79*gridDim (node_chunk<=512), n_edges <= 32*gridDim.
__global__ __launch_bounds__(COOP_THREADS) void sir_steps_kernel(
        const float* __restrict__ x,
        const int* __restrict__ edge_cnt, const int* __restrict__ edge_nodes,
        const int* __restrict__ node_cnt, const int* __restrict__ node_edges,
        const float* __restrict__ beta, const float* __restrict__ gamma,
        float* __restrict__ y, float* __restrict__ I,
        float* __restrict__ out,
        int n_nodes, int n_edges, int steps, unsigned* bar) {
    const int b  = blockIdx.x;
    const int tx = threadIdx.x;

    // ---- chunked ownership, spread across all 8 waves of the block ----
    const int node_chunk = (n_nodes + gridDim.x - 1) / gridDim.x;   // 79
    const int edge_chunk = (n_edges + gridDim.x - 1) / gridDim.x;   // 20
    const int wave = tx >> 6, lane = tx & 63;
    const int lslot = wave + (lane << 3);            // 0..511, bijective
    const int n = b * node_chunk + lslot;
    const bool own = (lslot < node_chunk) && (n < n_nodes);

    const int k = tx >> 4, gl = tx & 15;
    const int lg = (k & 3) * 8 + (k >> 2);           // 0..31, spread over waves
    const int e = b * edge_chunk + lg;
    const bool has_edge = (lg < edge_chunk) && (e < n_edges);

    // ---- preload adjacency into registers (dummy-padded: I[n_nodes]=y[n_edges]=0) ----
    int ecnt = 0;
    const int* en = edge_nodes;
    if (has_edge) { ecnt = min(edge_cnt[e], EDGE_CAP); en = edge_nodes + e * EDGE_CAP; }
    int eidx[6];
    #pragma unroll
    for (int i = 0; i < 6; ++i) {
        int j = i * 16 + gl;
        eidx[i] = (has_edge && j < ecnt) ? en[j] : n_nodes;
    }

    int ncnt = 0;
    const int* ne = node_edges;
    float bet = 0.0f, gam = 0.0f;
    if (own) { ncnt = min(node_cnt[n], NODE_CAP); ne = node_edges + n * NODE_CAP;
               bet = beta[n]; gam = gamma[n]; }
    int nidx[NIDX_REG];
    #pragma unroll
    for (int i = 0; i < NIDX_REG; ++i)
        nidx[i] = (own && i < ncnt) ? ne[i] : n_edges;

    // ---- init: state to regs, publish I, dummies, traj[0] ----
    float s = 0.0f, iv = 0.0f, r = 0.0f;
    if (own) {
        s = x[n * 3 + 0]; iv = x[n * 3 + 1]; r = x[n * 3 + 2];
        coh_storef(&I[n], iv);
        out[n * 3 + 0] = s; out[n * 3 + 1] = iv; out[n * 3 + 2] = r;
    }
    if (b == 0 && tx == 0) { coh_storef(&I[n_nodes], 0.0f); coh_storef(&y[n_edges], 0.0f); }
    unsigned phase = 1;
    bar_arrive(bar); bar_wait(bar, phase);

    for (int t = 1; t < steps; ++t) {
        // ---- edge phase: y[e] = sum I over edge members (16 lanes/edge) ----
        if (has_edge) {
            float a0 = coh_load(&I[eidx[0]]);
            float a1 = coh_load(&I[eidx[1]]);
            float a2 = coh_load(&I[eidx[2]]);
            float a3 = coh_load(&I[eidx[3]]);
            float a4 = coh_load(&I[eidx[4]]);
            float a5 = coh_load(&I[eidx[5]]);
            float acc = a0 + a1 + a2 + a3 + a4 + a5;   // trailing dummies add exact 0
            acc += __shfl_down(acc, 8, 16);
            acc += __shfl_down(acc, 4, 16);
            acc += __shfl_down(acc, 2, 16);
            acc += __shfl_down(acc, 1, 16);
            if (gl == 0) coh_storef(&y[e], acc);
        }
        ++phase; bar_arrive(bar); bar_wait(bar, phase);

        // ---- node phase: z = sum y over incident edges; SIR update in regs ----
        if (own) {
            float tv[NIDX_REG];
            #pragma unroll
            for (int i = 0; i < NIDX_REG; ++i) tv[i] = coh_load(&y[nidx[i]]);
            float z = 0.0f;
            #pragma unroll
            for (int i = 0; i < NIDX_REG; ++i) z += tv[i];   // in-order, dummies exact 0
            for (int i = NIDX_REG; i < ncnt; ++i) z += coh_load(&y[ne[i]]);  // rare tail
            float nc = bet * s * z;
            float nr = gam * iv;
            float s2 = fmaxf(s - nc, 0.0f);
            float i2 = fmaxf(iv + nc - nr, 0.0f);
            float r2 = fmaxf(r + nr, 0.0f);
            float inv = 1.0f / (s2 + i2 + r2);
            s = s2 * inv; iv = i2 * inv; r = r2 * inv;
            coh_storef(&I[n], iv);
        }
        ++phase; bar_arrive(bar);
        if (own) {   // trajectory store overlaps other blocks' barrier spin
            float* ot = out + (size_t)t * n_nodes * 3 + (size_t)n * 3;
            ot[0] = s; ot[1] = iv; ot[2] = r;
        }
        if (t + 1 < steps) bar_wait(bar, phase);
    }
}

extern "C" void kernel_launch(void* const* d_in, const int* in_sizes, int n_in,
                              void* d_out, int out_size, void* d_ws, size_t ws_size,
                              hipStream_t stream) {
    const float* x     = (const float*)d_in[0];
    const float* H     = (const float*)d_in[1];
    const float* beta  = (const float*)d_in[2];
    const float* gamma = (const float*)d_in[3];
    float* out = (float*)d_out;

    const int n_nodes = in_sizes[0] / 3;                 // 20000
    const int n_edges = in_sizes[1] / n_nodes;           // 5000
    const int steps   = out_size / in_sizes[0];          // 50

    // workspace carve-up (ints/floats are both 4B)
    char* ws = (char*)d_ws;
    unsigned* bar     = (unsigned*)ws;                    ws += BAR_UINTS * 4;
    int*   edge_cnt   = (int*)ws;                         ws += (size_t)n_edges * 4;
    int*   node_cnt   = (int*)ws;                         ws += (size_t)n_nodes * 4;
    int*   edge_nodes = (int*)ws;                         ws += (size_t)n_edges * EDGE_CAP * 4;
    int*   node_edges = (int*)ws;                         ws += (size_t)n_nodes * NODE_CAP * 4;
    float* y          = (float*)ws;                       ws += ((size_t)n_edges + 1) * 4;
    float* I          = (float*)ws;                       ws += ((size_t)n_nodes + 1) * 4;

    // 1. zero counters + barrier region (ws is poisoned 0xAA each call)
    {
        int mx = max(n_edges, max(n_nodes, BAR_UINTS));
        zero_counts_kernel<<<(mx + 255) / 256, 256, 0, stream>>>(edge_cnt, node_cnt, bar,
                                                                 n_edges, n_nodes);
    }
    // 2. extract sparsity of H (the one unavoidable 400MB scan)
    build_adjacency_kernel<<<n_edges, 256, 0, stream>>>(H, edge_cnt, edge_nodes,
                                                        node_cnt, node_edges, n_nodes);
    // 3. all SIR steps in one persistent kernel with tree barriers
    sir_steps_kernel<<<COOP_BLOCKS, COOP_THREADS, 0, stream>>>(
        x, edge_cnt, edge_nodes, node_cnt, node_edges, beta, gamma,
        y, I, out, n_nodes, n_edges, steps, bar);
}

// Round 4
// 1011.449 us; speedup vs baseline: 1.6093x; 1.0752x over previous
//
#include <hip/hip_runtime.h>

// HyperNetSIR: x(N,3) f32, H(E,N) f32 0/1 mask (density 0.002), beta(N), gamma(N), steps(int)
// out: (steps, N, 3) f32 trajectory.
//
// v4 strategy (persistent kernel, flat low-contention barrier):
//  * build_adjacency: LDS-compacted per-row nonzero extraction, coalesced
//    writeout + batched global atomics (v3, unchanged).
//  * sir_steps: 256 blocks x 512 threads (1 block/CU, all co-resident).
//    - tx-contiguous chunked ownership: block b owns nodes [b*79..), edges
//      [b*20..). Contiguous => coalesced trajectory stores (v3's interleaved
//      slots caused 5x write amplification: WRITE_SIZE 18->52MB), coalesced
//      I publish and x/beta/gamma loads. Idle waves just arrive early.
//    - adjacency indices preloaded into registers (dummy-padded) => per-step
//      gathers are branch-free independent coherent loads (full MLP).
//    - cross-XCD data (I, y) via sc-flagged relaxed agent atomics.
//    - barrier v4: 2-hop flat barrier. Arrive = one agent RMW into one of 8
//      counter lines (<=32 blocks per line, 512B apart). Wait = thread0 of
//      every block polls all 8 lines and sums (reads pipeline; no root hop,
//      no leader hop, no 256-poller single line). v3's 2-level tree cost
//      ~4-5us/barrier from a 4-hop serial chain of L3 round trips.

#define EDGE_CAP 96   // max nodes per edge (mean 40, sigma 6.3)
#define NODE_CAP 32   // max edges per node (mean 10, sigma 3.2)
#define NIDX_REG 16   // node-adjacency indices held in registers (P(cnt>16) ~ 3%)
#define COOP_BLOCKS 256
#define COOP_THREADS 512
#define BAR_LINES 8
#define BAR_STRIDE 128                    // u32s -> 512B between counter lines
#define BAR_UINTS (BAR_LINES * BAR_STRIDE)

__global__ void zero_counts_kernel(int* edge_cnt, int* node_cnt, unsigned* bar,
                                   int n_edges, int n_nodes) {
    int i = blockIdx.x * blockDim.x + threadIdx.x;
    if (i < BAR_UINTS) bar[i] = 0u;
    if (i < n_edges) edge_cnt[i] = 0;
    if (i < n_nodes) node_cnt[i] = 0;
}

// One block per edge row. Compact nonzero columns into LDS (cheap LDS atomics),
// then write the edge list coalesced and do the node-side scatter with one
// batched wave of global atomics.
__global__ void build_adjacency_kernel(const float* __restrict__ H,
                                       int* __restrict__ edge_cnt,
                                       int* __restrict__ edge_nodes,
                                       int* __restrict__ node_cnt,
                                       int* __restrict__ node_edges,
                                       int n_nodes) {
    __shared__ int cnt;
    __shared__ int cols[EDGE_CAP];
    const int e = blockIdx.x;
    if (threadIdx.x == 0) cnt = 0;
    __syncthreads();
    const uint4* row4 = (const uint4*)(H + (size_t)e * n_nodes);
    const int n4 = n_nodes >> 2;
    for (int c4 = threadIdx.x; c4 < n4; c4 += blockDim.x) {
        uint4 v = row4[c4];
        if ((v.x | v.y | v.z | v.w) != 0u) {   // H is a 0/1 mask; bit test ok
            int cbase = c4 << 2;
            if (v.x) { int p = atomicAdd(&cnt, 1); if (p < EDGE_CAP) cols[p] = cbase; }
            if (v.y) { int p = atomicAdd(&cnt, 1); if (p < EDGE_CAP) cols[p] = cbase + 1; }
            if (v.z) { int p = atomicAdd(&cnt, 1); if (p < EDGE_CAP) cols[p] = cbase + 2; }
            if (v.w) { int p = atomicAdd(&cnt, 1); if (p < EDGE_CAP) cols[p] = cbase + 3; }
        }
    }
    if (threadIdx.x == 0) {   // tail (n_nodes not multiple of 4)
        const float* row = H + (size_t)e * n_nodes;
        for (int c = n4 << 2; c < n_nodes; ++c)
            if (row[c] != 0.0f) { int p = atomicAdd(&cnt, 1); if (p < EDGE_CAP) cols[p] = c; }
    }
    __syncthreads();
    int cn = min(cnt, EDGE_CAP);
    if (threadIdx.x == 0) edge_cnt[e] = cn;
    for (int i = threadIdx.x; i < cn; i += blockDim.x) {
        int c = cols[i];
        edge_nodes[e * EDGE_CAP + i] = c;
        int q = atomicAdd(&node_cnt[c], 1);           // device-scope, batched
        if (q < NODE_CAP) node_edges[c * NODE_CAP + q] = e;
    }
}

// Coherent (cross-XCD) access helpers: sc-flagged, bypass non-coherent L1/L2.
__device__ __forceinline__ float coh_load(const float* p) {
    return __hip_atomic_load(p, __ATOMIC_RELAXED, __HIP_MEMORY_SCOPE_AGENT);
}
__device__ __forceinline__ void coh_storef(float* p, float v) {
    __hip_atomic_store(p, v, __ATOMIC_RELAXED, __HIP_MEMORY_SCOPE_AGENT);
}

// Flat 2-hop barrier. Arrive: drain my coherent stores (per-wave vmcnt 0),
// block-sync, thread0 RMWs one of 8 spread counter lines (<=32 RMW actors per
// line). Wait: thread0 sums all 8 lines until the global arrival count hits
// the target. Monotonic counters + relaxed atomic loads: stale reads only
// delay, never false-positive.
__device__ __forceinline__ void bar_arrive(unsigned* bar) {
    asm volatile("s_waitcnt vmcnt(0)" ::: "memory");
    __syncthreads();
    if (threadIdx.x == 0)
        __hip_atomic_fetch_add(&bar[(blockIdx.x & (BAR_LINES - 1)) * BAR_STRIDE], 1u,
                               __ATOMIC_RELAXED, __HIP_MEMORY_SCOPE_AGENT);
}
__device__ __forceinline__ void bar_wait(unsigned* bar, unsigned target) {
    if (threadIdx.x == 0) {
        for (;;) {
            unsigned sum = 0;
            #pragma unroll
            for (int i = 0; i < BAR_LINES; ++i)
                sum += __hip_atomic_load(&bar[i * BAR_STRIDE], __ATOMIC_RELAXED,
                                         __HIP_MEMORY_SCOPE_AGENT);
            if (sum >= target) break;
            __builtin_amdgcn_s_sleep(1);
        }
    }
    __syncthreads();
    asm volatile("" ::: "memory");
}

// All SIR steps in one persistent kernel.
// Requires: n_nodes <= node_chunk*gridDim with node_chunk <= blockDim,
//           n_edges <= 32*gridDim.
__global__ __launch_bounds__(COOP_THREADS) void sir_steps_kernel(
        const float* __restrict__ x,
        const int* __restrict__ edge_cnt, const int* __restrict__ edge_nodes,
        const int* __restrict__ node_cnt, const int* __restrict__ node_edges,
        const float* __restrict__ beta, const float* __restrict__ gamma,
        float* __restrict__ y, float* __restrict__ I,
        float* __restrict__ out,
        int n_nodes, int n_edges, int steps, unsigned* bar) {
    const int b  = blockIdx.x;
    const int tx = threadIdx.x;

    // ---- tx-contiguous chunked ownership ----
    const int node_chunk = (n_nodes + gridDim.x - 1) / gridDim.x;   // 79
    const int edge_chunk = (n_edges + gridDim.x - 1) / gridDim.x;   // 20
    const int n = b * node_chunk + tx;
    const bool own = (tx < node_chunk) && (n < n_nodes);

    const int k = tx >> 4, gl = tx & 15;       // 16 lanes per edge
    const int e = b * edge_chunk + k;
    const bool has_edge = (k < edge_chunk) && (e < n_edges);

    // ---- preload adjacency into registers (dummy-padded: I[n_nodes]=y[n_edges]=0) ----
    int ecnt = 0;
    const int* en = edge_nodes;
    if (has_edge) { ecnt = min(edge_cnt[e], EDGE_CAP); en = edge_nodes + e * EDGE_CAP; }
    int eidx[6];
    #pragma unroll
    for (int i = 0; i < 6; ++i) {
        int j = i * 16 + gl;
        eidx[i] = (has_edge && j < ecnt) ? en[j] : n_nodes;
    }

    int ncnt = 0;
    const int* ne = node_edges;
    float bet = 0.0f, gam = 0.0f;
    if (own) { ncnt = min(node_cnt[n], NODE_CAP); ne = node_edges + n * NODE_CAP;
               bet = beta[n]; gam = gamma[n]; }
    int nidx[NIDX_REG];
    #pragma unroll
    for (int i = 0; i < NIDX_REG; ++i)
        nidx[i] = (own && i < ncnt) ? ne[i] : n_edges;

    // ---- init: state to regs, publish I, dummies, traj[0] ----
    float s = 0.0f, iv = 0.0f, r = 0.0f;
    if (own) {
        s = x[n * 3 + 0]; iv = x[n * 3 + 1]; r = x[n * 3 + 2];
        coh_storef(&I[n], iv);
        out[n * 3 + 0] = s; out[n * 3 + 1] = iv; out[n * 3 + 2] = r;
    }
    if (b == 0 && tx == 0) { coh_storef(&I[n_nodes], 0.0f); coh_storef(&y[n_edges], 0.0f); }
    unsigned bars = 0;
    bar_arrive(bar); bars += gridDim.x; bar_wait(bar, bars);

    for (int t = 1; t < steps; ++t) {
        // ---- edge phase: y[e] = sum I over edge members (16 lanes/edge) ----
        if (has_edge) {
            float a0 = coh_load(&I[eidx[0]]);
            float a1 = coh_load(&I[eidx[1]]);
            float a2 = coh_load(&I[eidx[2]]);
            float a3 = coh_load(&I[eidx[3]]);
            float a4 = coh_load(&I[eidx[4]]);
            float a5 = coh_load(&I[eidx[5]]);
            float acc = a0 + a1 + a2 + a3 + a4 + a5;   // trailing dummies add exact 0
            acc += __shfl_down(acc, 8, 16);
            acc += __shfl_down(acc, 4, 16);
            acc += __shfl_down(acc, 2, 16);
            acc += __shfl_down(acc, 1, 16);
            if (gl == 0) coh_storef(&y[e], acc);
        }
        bar_arrive(bar); bars += gridDim.x; bar_wait(bar, bars);

        // ---- node phase: z = sum y over incident edges; SIR update in regs ----
        if (own) {
            float tv[NIDX_REG];
            #pragma unroll
            for (int i = 0; i < NIDX_REG; ++i) tv[i] = coh_load(&y[nidx[i]]);
            float z = 0.0f;
            #pragma unroll
            for (int i = 0; i < NIDX_REG; ++i) z += tv[i];   // in-order, dummies exact 0
            for (int i = NIDX_REG; i < ncnt; ++i) z += coh_load(&y[ne[i]]);  // rare tail
            float nc = bet * s * z;
            float nr = gam * iv;
            float s2 = fmaxf(s - nc, 0.0f);
            float i2 = fmaxf(iv + nc - nr, 0.0f);
            float r2 = fmaxf(r + nr, 0.0f);
            float inv = 1.0f / (s2 + i2 + r2);
            s = s2 * inv; iv = i2 * inv; r = r2 * inv;
            coh_storef(&I[n], iv);
        }
        bar_arrive(bar); bars += gridDim.x;
        if (own) {   // coalesced trajectory store overlaps other blocks' spin
            float* ot = out + (size_t)t * n_nodes * 3 + (size_t)n * 3;
            ot[0] = s; ot[1] = iv; ot[2] = r;
        }
        if (t + 1 < steps) bar_wait(bar, bars);
    }
}

extern "C" void kernel_launch(void* const* d_in, const int* in_sizes, int n_in,
                              void* d_out, int out_size, void* d_ws, size_t ws_size,
                              hipStream_t stream) {
    const float* x     = (const float*)d_in[0];
    const float* H     = (const float*)d_in[1];
    const float* beta  = (const float*)d_in[2];
    const float* gamma = (const float*)d_in[3];
    float* out = (float*)d_out;

    const int n_nodes = in_sizes[0] / 3;                 // 20000
    const int n_edges = in_sizes[1] / n_nodes;           // 5000
    const int steps   = out_size / in_sizes[0];          // 50

    // workspace carve-up (ints/floats are both 4B)
    char* ws = (char*)d_ws;
    unsigned* bar     = (unsigned*)ws;                    ws += (size_t)BAR_UINTS * 4;
    int*   edge_cnt   = (int*)ws;                         ws += (size_t)n_edges * 4;
    int*   node_cnt   = (int*)ws;                         ws += (size_t)n_nodes * 4;
    int*   edge_nodes = (int*)ws;                         ws += (size_t)n_edges * EDGE_CAP * 4;
    int*   node_edges = (int*)ws;                         ws += (size_t)n_nodes * NODE_CAP * 4;
    float* y          = (float*)ws;                       ws += ((size_t)n_edges + 1) * 4;
    float* I          = (float*)ws;                       ws += ((size_t)n_nodes + 1) * 4;

    // 1. zero counters + barrier region (ws is poisoned 0xAA each call)
    {
        int mx = max(n_edges, max(n_nodes, (int)BAR_UINTS));
        zero_counts_kernel<<<(mx + 255) / 256, 256, 0, stream>>>(edge_cnt, node_cnt, bar,
                                                                 n_edges, n_nodes);
    }
    // 2. extract sparsity of H (the one unavoidable 400MB scan)
    build_adjacency_kernel<<<n_edges, 256, 0, stream>>>(H, edge_cnt, edge_nodes,
                                                        node_cnt, node_edges, n_nodes);
    // 3. all SIR steps in one persistent kernel with flat 2-hop barriers
    sir_steps_kernel<<<COOP_BLOCKS, COOP_THREADS, 0, stream>>>(
        x, edge_cnt, edge_nodes, node_cnt, node_edges, beta, gamma,
        y, I, out, n_nodes, n_edges, steps, bar);
}

// Round 6
// 981.209 us; speedup vs baseline: 1.6589x; 1.0308x over previous
//
#include <hip/hip_runtime.h>

// HyperNetSIR: x(N,3) f32, H(E,N) f32 0/1 mask (density 0.002), beta(N), gamma(N), steps(int)
// out: (steps, N, 3) f32 trajectory.
//
// v5b strategy (persistent kernel, fewer/fatter blocks):
//  * build_adjacency: LDS-compacted per-row nonzero extraction; 2-wide
//    unrolled NONTEMPORAL loads via a clang ext_vector_type (HIP's uint4 is a
//    class and rejected by __builtin_nontemporal_load). 2x MLP on the 400MB
//    stream; nt avoids polluting L2/L3 with single-use H lines.
//  * sir_steps: 128 blocks x 1024 threads (1 block/CU on 128 CUs, 16 waves/CU
//    for jitter absorption; all co-resident).
//    - tx-contiguous chunked ownership (coalesced traj stores / I publish).
//    - adjacency indices preloaded into registers (dummy-padded) => per-step
//      gathers are branch-free independent coherent loads (full MLP).
//    - cross-XCD data (I, y) via sc-flagged relaxed agent atomics.
//    - flat 2-hop barrier, 8 counter lines; halves arrival count (128 RMWs)
//      and max-of-N skew vs v4's 256 blocks.

#define EDGE_CAP 96   // max nodes per edge (mean 40, sigma 6.3)
#define NODE_CAP 32   // max edges per node (mean 10, sigma 3.2)
#define NIDX_REG 16   // node-adjacency indices held in registers (P(cnt>16) ~ 3%)
#define COOP_BLOCKS 128
#define COOP_THREADS 1024
#define BAR_LINES 8
#define BAR_STRIDE 128                    // u32s -> 512B between counter lines
#define BAR_UINTS (BAR_LINES * BAR_STRIDE)

typedef unsigned int uint4_ev __attribute__((ext_vector_type(4)));

__global__ void zero_counts_kernel(int* edge_cnt, int* node_cnt, unsigned* bar,
                                   int n_edges, int n_nodes) {
    int i = blockIdx.x * blockDim.x + threadIdx.x;
    if (i < BAR_UINTS) bar[i] = 0u;
    if (i < n_edges) edge_cnt[i] = 0;
    if (i < n_nodes) node_cnt[i] = 0;
}

// One block per edge row. Compact nonzero columns into LDS (cheap LDS atomics),
// then write the edge list coalesced and do the node-side scatter with one
// batched wave of global atomics. Row scan: 2 independent nontemporal 16B
// loads per iteration (MLP; don't pollute caches with the single-use stream).
__global__ void build_adjacency_kernel(const float* __restrict__ H,
                                       int* __restrict__ edge_cnt,
                                       int* __restrict__ edge_nodes,
                                       int* __restrict__ node_cnt,
                                       int* __restrict__ node_edges,
                                       int n_nodes) {
    __shared__ int cnt;
    __shared__ int cols[EDGE_CAP];
    const int e = blockIdx.x;
    if (threadIdx.x == 0) cnt = 0;
    __syncthreads();
    const uint4_ev* row4 = (const uint4_ev*)(H + (size_t)e * n_nodes);
    const int n4 = n_nodes >> 2;
    for (int c4 = threadIdx.x; c4 < n4; c4 += 2 * blockDim.x) {
        int c4b = c4 + blockDim.x;
        uint4_ev v0 = __builtin_nontemporal_load(&row4[c4]);
        uint4_ev v1 = (c4b < n4) ? __builtin_nontemporal_load(&row4[c4b])
                                 : (uint4_ev){0u, 0u, 0u, 0u};
        if ((v0.x | v0.y | v0.z | v0.w) != 0u) {   // H is a 0/1 mask; bit test ok
            int cbase = c4 << 2;
            if (v0.x) { int p = atomicAdd(&cnt, 1); if (p < EDGE_CAP) cols[p] = cbase; }
            if (v0.y) { int p = atomicAdd(&cnt, 1); if (p < EDGE_CAP) cols[p] = cbase + 1; }
            if (v0.z) { int p = atomicAdd(&cnt, 1); if (p < EDGE_CAP) cols[p] = cbase + 2; }
            if (v0.w) { int p = atomicAdd(&cnt, 1); if (p < EDGE_CAP) cols[p] = cbase + 3; }
        }
        if ((v1.x | v1.y | v1.z | v1.w) != 0u) {
            int cbase = c4b << 2;
            if (v1.x) { int p = atomicAdd(&cnt, 1); if (p < EDGE_CAP) cols[p] = cbase; }
            if (v1.y) { int p = atomicAdd(&cnt, 1); if (p < EDGE_CAP) cols[p] = cbase + 1; }
            if (v1.z) { int p = atomicAdd(&cnt, 1); if (p < EDGE_CAP) cols[p] = cbase + 2; }
            if (v1.w) { int p = atomicAdd(&cnt, 1); if (p < EDGE_CAP) cols[p] = cbase + 3; }
        }
    }
    if (threadIdx.x == 0) {   // tail (n_nodes not multiple of 4)
        const float* row = H + (size_t)e * n_nodes;
        for (int c = n4 << 2; c < n_nodes; ++c)
            if (row[c] != 0.0f) { int p = atomicAdd(&cnt, 1); if (p < EDGE_CAP) cols[p] = c; }
    }
    __syncthreads();
    int cn = min(cnt, EDGE_CAP);
    if (threadIdx.x == 0) edge_cnt[e] = cn;
    for (int i = threadIdx.x; i < cn; i += blockDim.x) {
        int c = cols[i];
        edge_nodes[e * EDGE_CAP + i] = c;
        int q = atomicAdd(&node_cnt[c], 1);           // device-scope, batched
        if (q < NODE_CAP) node_edges[c * NODE_CAP + q] = e;
    }
}

// Coherent (cross-XCD) access helpers: sc-flagged, bypass non-coherent L1/L2.
__device__ __forceinline__ float coh_load(const float* p) {
    return __hip_atomic_load(p, __ATOMIC_RELAXED, __HIP_MEMORY_SCOPE_AGENT);
}
__device__ __forceinline__ void coh_storef(float* p, float v) {
    __hip_atomic_store(p, v, __ATOMIC_RELAXED, __HIP_MEMORY_SCOPE_AGENT);
}

// Flat 2-hop barrier. Arrive: drain my coherent stores (per-wave vmcnt 0),
// block-sync, thread0 RMWs one of 8 spread counter lines (<=16 RMW actors per
// line). Wait: thread0 sums all 8 lines until the global arrival count hits
// the target. Monotonic counters + relaxed atomic loads: stale reads only
// delay, never false-positive.
__device__ __forceinline__ void bar_arrive(unsigned* bar) {
    asm volatile("s_waitcnt vmcnt(0)" ::: "memory");
    __syncthreads();
    if (threadIdx.x == 0)
        __hip_atomic_fetch_add(&bar[(blockIdx.x & (BAR_LINES - 1)) * BAR_STRIDE], 1u,
                               __ATOMIC_RELAXED, __HIP_MEMORY_SCOPE_AGENT);
}
__device__ __forceinline__ void bar_wait(unsigned* bar, unsigned target) {
    if (threadIdx.x == 0) {
        for (;;) {
            unsigned sum = 0;
            #pragma unroll
            for (int i = 0; i < BAR_LINES; ++i)
                sum += __hip_atomic_load(&bar[i * BAR_STRIDE], __ATOMIC_RELAXED,
                                         __HIP_MEMORY_SCOPE_AGENT);
            if (sum >= target) break;
            __builtin_amdgcn_s_sleep(1);
        }
    }
    __syncthreads();
    asm volatile("" ::: "memory");
}

// All SIR steps in one persistent kernel.
// Requires: n_nodes <= node_chunk*gridDim with node_chunk <= blockDim,
//           n_edges <= (blockDim/16)*gridDim.
__global__ __launch_bounds__(COOP_THREADS) void sir_steps_kernel(
        const float* __restrict__ x,
        const int* __restrict__ edge_cnt, const int* __restrict__ edge_nodes,
        const int* __restrict__ node_cnt, const int* __restrict__ node_edges,
        const float* __restrict__ beta, const float* __restrict__ gamma,
        float* __restrict__ y, float* __restrict__ I,
        float* __restrict__ out,
        int n_nodes, int n_edges, int steps, unsigned* bar) {
    const int b  = blockIdx.x;
    const int tx = threadIdx.x;

    // ---- tx-contiguous chunked ownership ----
    const int node_chunk = (n_nodes + gridDim.x - 1) / gridDim.x;   // 157
    const int edge_chunk = (n_edges + gridDim.x - 1) / gridDim.x;   // 40
    const int n = b * node_chunk + tx;
    const bool own = (tx < node_chunk) && (n < n_nodes);

    const int k = tx >> 4, gl = tx & 15;       // 16 lanes per edge, 64 groups/block
    const int e = b * edge_chunk + k;
    const bool has_edge = (k < edge_chunk) && (e < n_edges);

    // ---- preload adjacency into registers (dummy-padded: I[n_nodes]=y[n_edges]=0) ----
    int ecnt = 0;
    const int* en = edge_nodes;
    if (has_edge) { ecnt = min(edge_cnt[e], EDGE_CAP); en = edge_nodes + e * EDGE_CAP; }
    int eidx[6];
    #pragma unroll
    for (int i = 0; i < 6; ++i) {
        int j = i * 16 + gl;
        eidx[i] = (has_edge && j < ecnt) ? en[j] : n_nodes;
    }

    int ncnt = 0;
    const int* ne = node_edges;
    float bet = 0.0f, gam = 0.0f;
    if (own) { ncnt = min(node_cnt[n], NODE_CAP); ne = node_edges + n * NODE_CAP;
               bet = beta[n]; gam = gamma[n]; }
    int nidx[NIDX_REG];
    #pragma unroll
    for (int i = 0; i < NIDX_REG; ++i)
        nidx[i] = (own && i < ncnt) ? ne[i] : n_edges;

    // ---- init: state to regs, publish I, dummies, traj[0] ----
    float s = 0.0f, iv = 0.0f, r = 0.0f;
    if (own) {
        s = x[n * 3 + 0]; iv = x[n * 3 + 1]; r = x[n * 3 + 2];
        coh_storef(&I[n], iv);
        out[n * 3 + 0] = s; out[n * 3 + 1] = iv; out[n * 3 + 2] = r;
    }
    if (b == 0 && tx == 0) { coh_storef(&I[n_nodes], 0.0f); coh_storef(&y[n_edges], 0.0f); }
    unsigned bars = 0;
    bar_arrive(bar); bars += gridDim.x; bar_wait(bar, bars);

    for (int t = 1; t < steps; ++t) {
        // ---- edge phase: y[e] = sum I over edge members (16 lanes/edge) ----
        if (has_edge) {
            float a0 = coh_load(&I[eidx[0]]);
            float a1 = coh_load(&I[eidx[1]]);
            float a2 = coh_load(&I[eidx[2]]);
            float a3 = coh_load(&I[eidx[3]]);
            float a4 = coh_load(&I[eidx[4]]);
            float a5 = coh_load(&I[eidx[5]]);
            float acc = a0 + a1 + a2 + a3 + a4 + a5;   // trailing dummies add exact 0
            acc += __shfl_down(acc, 8, 16);
            acc += __shfl_down(acc, 4, 16);
            acc += __shfl_down(acc, 2, 16);
            acc += __shfl_down(acc, 1, 16);
            if (gl == 0) coh_storef(&y[e], acc);
        }
        bar_arrive(bar); bars += gridDim.x; bar_wait(bar, bars);

        // ---- node phase: z = sum y over incident edges; SIR update in regs ----
        if (own) {
            float tv[NIDX_REG];
            #pragma unroll
            for (int i = 0; i < NIDX_REG; ++i) tv[i] = coh_load(&y[nidx[i]]);
            float z = 0.0f;
            #pragma unroll
            for (int i = 0; i < NIDX_REG; ++i) z += tv[i];   // in-order, dummies exact 0
            for (int i = NIDX_REG; i < ncnt; ++i) z += coh_load(&y[ne[i]]);  // rare tail
            float nc = bet * s * z;
            float nr = gam * iv;
            float s2 = fmaxf(s - nc, 0.0f);
            float i2 = fmaxf(iv + nc - nr, 0.0f);
            float r2 = fmaxf(r + nr, 0.0f);
            float inv = 1.0f / (s2 + i2 + r2);
            s = s2 * inv; iv = i2 * inv; r = r2 * inv;
            coh_storef(&I[n], iv);
        }
        bar_arrive(bar); bars += gridDim.x;
        if (own) {   // coalesced trajectory store overlaps other blocks' spin
            float* ot = out + (size_t)t * n_nodes * 3 + (size_t)n * 3;
            ot[0] = s; ot[1] = iv; ot[2] = r;
        }
        if (t + 1 < steps) bar_wait(bar, bars);
    }
}

extern "C" void kernel_launch(void* const* d_in, const int* in_sizes, int n_in,
                              void* d_out, int out_size, void* d_ws, size_t ws_size,
                              hipStream_t stream) {
    const float* x     = (const float*)d_in[0];
    const float* H     = (const float*)d_in[1];
    const float* beta  = (const float*)d_in[2];
    const float* gamma = (const float*)d_in[3];
    float* out = (float*)d_out;

    const int n_nodes = in_sizes[0] / 3;                 // 20000
    const int n_edges = in_sizes[1] / n_nodes;           // 5000
    const int steps   = out_size / in_sizes[0];          // 50

    // workspace carve-up (ints/floats are both 4B)
    char* ws = (char*)d_ws;
    unsigned* bar     = (unsigned*)ws;                    ws += (size_t)BAR_UINTS * 4;
    int*   edge_cnt   = (int*)ws;                         ws += (size_t)n_edges * 4;
    int*   node_cnt   = (int*)ws;                         ws += (size_t)n_nodes * 4;
    int*   edge_nodes = (int*)ws;                         ws += (size_t)n_edges * EDGE_CAP * 4;
    int*   node_edges = (int*)ws;                         ws += (size_t)n_nodes * NODE_CAP * 4;
    float* y          = (float*)ws;                       ws += ((size_t)n_edges + 1) * 4;
    float* I          = (float*)ws;                       ws += ((size_t)n_nodes + 1) * 4;

    // 1. zero counters + barrier region (ws is poisoned 0xAA each call)
    {
        int mx = max(n_edges, max(n_nodes, (int)BAR_UINTS));
        zero_counts_kernel<<<(mx + 255) / 256, 256, 0, stream>>>(edge_cnt, node_cnt, bar,
                                                                 n_edges, n_nodes);
    }
    // 2. extract sparsity of H (the one unavoidable 400MB scan)
    build_adjacency_kernel<<<n_edges, 256, 0, stream>>>(H, edge_cnt, edge_nodes,
                                                        node_cnt, node_edges, n_nodes);
    // 3. all SIR steps in one persistent kernel with flat 2-hop barriers
    sir_steps_kernel<<<COOP_BLOCKS, COOP_THREADS, 0, stream>>>(
        x, edge_cnt, edge_nodes, node_cnt, node_edges, beta, gamma,
        y, I, out, n_nodes, n_edges, steps, bar);
}